// Round 8
// baseline (176.608 us; speedup 1.0000x reference)
//
#include <hip/hip_runtime.h>
#include <math.h>

#define B_SZ 2
#define HH 64
#define WW 64
#define DM 192
#define NS 16
#define RR 12
#define KD 4
#define LL (HH * WW)           // 4096
#define CPROJ (RR + 2 * NS)    // 44
#define CPAD 48
#define NCH 256
#define CH (LL / NCH)          // 16 steps per chunk
#define NBLK (B_SZ * KD * NCH) // 2048 blocks
#define TLP 64                 // l-tile per proj block
#define LOG2E 1.44269504088896340736f
#define LN2F 0.69314718055994530942f

// component i (compile-time after unroll) of a float4 register array
#define RQF(arr, i) (((i) & 3) == 0 ? arr[(i) >> 2].x : ((i) & 3) == 1 ? arr[(i) >> 2].y \
                     : ((i) & 3) == 2 ? arr[(i) >> 2].z : arr[(i) >> 2].w)

// spatial index (row-major h*W+w) that scan position t of direction k touches
__device__ __forceinline__ int spatial_idx(int k, int t) {
    if (k == 0) return t;
    if (k == 1) return ((t & 63) << 6) | (t >> 6);          // t = w*H + h -> l = h*W + w
    if (k == 2) return LL - 1 - t;
    int tp = LL - 1 - t;
    return ((tp & 63) << 6) | (tp >> 6);
}

__device__ __forceinline__ void compute_dA(float dt, const float* Avl2, bool pw, float* dA) {
    if (pw) {
        float e1 = exp2f(dt * Avl2[0]);
        dA[0] = e1;
        dA[1] = e1 * e1;
        dA[2] = dA[1] * e1;
        dA[3] = dA[1] * dA[1];
        dA[4] = dA[3] * e1;
        dA[5] = dA[3] * dA[1];
        dA[6] = dA[3] * dA[2];
        dA[7] = dA[3] * dA[3];
        dA[8] = dA[7] * e1;
        dA[9] = dA[7] * dA[1];
        dA[10] = dA[7] * dA[2];
        dA[11] = dA[7] * dA[3];
        dA[12] = dA[7] * dA[4];
        dA[13] = dA[7] * dA[5];
        dA[14] = dA[7] * dA[6];
        dA[15] = dA[7] * dA[7];
    } else {
#pragma unroll
        for (int n = 0; n < NS; ++n) dA[n] = exp2f(dt * Avl2[n]);
    }
}

__device__ __forceinline__ void load_params(int kd, const float* __restrict__ dtw,
                                            const float* __restrict__ dtb,
                                            const float* __restrict__ Alogs,
                                            float* Wdt, float& bias, float* Avl2, bool& pw) {
#pragma unroll
    for (int r = 0; r < RR; ++r) Wdt[r] = dtw[(size_t)kd * RR + r];
    bias = dtb[kd];
#pragma unroll
    for (int n = 0; n < NS; ++n) Avl2[n] = -__expf(Alogs[(size_t)kd * NS + n]) * LOG2E;
    bool pws = true;
#pragma unroll
    for (int n = 0; n < NS; ++n)
        pws = pws && (fabsf(Avl2[n] - (float)(n + 1) * Avl2[0]) <= 1e-5f * fabsf(Avl2[n]) + 1e-30f);
    pw = (__all(pws ? 1 : 0) != 0);
}

// ---------------- chunked selective scan, phases 1 (carries) and 3 (emit y) ----------------
// CH=16 small chunks -> 2048 blocks -> 8 blocks/CU, 24 waves/CU: latency hidden by TLP.
// x is read directly from global inside the loop (full unroll lets the compiler hoist loads).
template <int PHASE>
__global__ __launch_bounds__(192) void scan_kernel(
    const float* __restrict__ x, const float* __restrict__ xdbl,
    const float* __restrict__ dtw, const float* __restrict__ dtb,
    const float* __restrict__ Alogs, const float* __restrict__ Ds,
    float* __restrict__ carry, float* __restrict__ aprod, float* __restrict__ ybuf4) {
    const int chunk = blockIdx.x & (NCH - 1);
    const int bk = blockIdx.x >> 8;
    const int k = bk & 3, b = bk >> 2;
    const int d = threadIdx.x;                 // 0..191
    const int kd = k * DM + d;
    const int tbase = chunk * CH;

    __shared__ float xds[CH * CPAD];           // 3 KB: xdbl chunk (16 rows x 48)

    // stage xdbl chunk: 192 float4, exactly 1 per thread
    {
        float4* dst = (float4*)xds;
        const float4* src = (const float4*)(xdbl + ((size_t)bk * LL + tbase) * CPAD);
        dst[threadIdx.x] = src[threadIdx.x];
    }
    __syncthreads();

    float Wdt[RR], bias, Avl2[NS];
    bool pw;
    load_params(kd, dtw, dtb, Alogs, Wdt, bias, Avl2, pw);
    const float Dval = (PHASE == 3) ? Ds[kd] : 0.f;

    const size_t cbase = ((size_t)blockIdx.x * DM + d) * NS;
    float h[NS];
    if (PHASE == 1) {
#pragma unroll
        for (int n = 0; n < NS; ++n) h[n] = 0.f;
    } else {
#pragma unroll
        for (int n = 0; n < NS; ++n) h[n] = carry[cbase + n];   // h_in from fix_kernel
    }
    float dtsum = 0.f;
    const float* xb = x + (size_t)b * LL * DM + d;
    float* yk = ybuf4 + (size_t)k * ((size_t)B_SZ * LL * DM) + (size_t)b * LL * DM + d;

#pragma unroll
    for (int tt = 0; tt < CH; ++tt) {
        const float4* r4 = (const float4*)(xds + tt * CPAD);
        float4 rq[11];
#pragma unroll
        for (int q = 0; q < (PHASE == 1 ? 7 : 11); ++q) rq[q] = r4[q];
        // dt projection, two-way split FMA chains
        float z0 = fmaf(RQF(rq, 0), Wdt[0], fmaf(RQF(rq, 2), Wdt[2], fmaf(RQF(rq, 4), Wdt[4],
                   fmaf(RQF(rq, 6), Wdt[6], fmaf(RQF(rq, 8), Wdt[8], RQF(rq, 10) * Wdt[10])))));
        float z1 = fmaf(RQF(rq, 1), Wdt[1], fmaf(RQF(rq, 3), Wdt[3], fmaf(RQF(rq, 5), Wdt[5],
                   fmaf(RQF(rq, 7), Wdt[7], fmaf(RQF(rq, 9), Wdt[9], RQF(rq, 11) * Wdt[11])))));
        float z = bias + z0 + z1;
        float dt = (z > 15.f) ? z : __log2f(1.f + exp2f(z * LOG2E)) * LN2F;
        int s = spatial_idx(k, tbase + tt);
        float xv = xb[(size_t)s * DM];
        float dtx = dt * xv;
        float dA[NS];
        compute_dA(dt, Avl2, pw, dA);
        if (PHASE == 1) {
            dtsum += dt;
#pragma unroll
            for (int n = 0; n < NS; ++n)
                h[n] = fmaf(dA[n], h[n], dtx * RQF(rq, RR + n));
        } else {
            float y0 = 0.f, y1 = 0.f, y2 = 0.f, y3 = 0.f;
            h[0]  = fmaf(dA[0],  h[0],  dtx * RQF(rq, 12));  y0 = fmaf(h[0],  RQF(rq, 28), y0);
            h[1]  = fmaf(dA[1],  h[1],  dtx * RQF(rq, 13));  y1 = fmaf(h[1],  RQF(rq, 29), y1);
            h[2]  = fmaf(dA[2],  h[2],  dtx * RQF(rq, 14));  y2 = fmaf(h[2],  RQF(rq, 30), y2);
            h[3]  = fmaf(dA[3],  h[3],  dtx * RQF(rq, 15));  y3 = fmaf(h[3],  RQF(rq, 31), y3);
            h[4]  = fmaf(dA[4],  h[4],  dtx * RQF(rq, 16));  y0 = fmaf(h[4],  RQF(rq, 32), y0);
            h[5]  = fmaf(dA[5],  h[5],  dtx * RQF(rq, 17));  y1 = fmaf(h[5],  RQF(rq, 33), y1);
            h[6]  = fmaf(dA[6],  h[6],  dtx * RQF(rq, 18));  y2 = fmaf(h[6],  RQF(rq, 34), y2);
            h[7]  = fmaf(dA[7],  h[7],  dtx * RQF(rq, 19));  y3 = fmaf(h[7],  RQF(rq, 35), y3);
            h[8]  = fmaf(dA[8],  h[8],  dtx * RQF(rq, 20));  y0 = fmaf(h[8],  RQF(rq, 36), y0);
            h[9]  = fmaf(dA[9],  h[9],  dtx * RQF(rq, 21));  y1 = fmaf(h[9],  RQF(rq, 37), y1);
            h[10] = fmaf(dA[10], h[10], dtx * RQF(rq, 22));  y2 = fmaf(h[10], RQF(rq, 38), y2);
            h[11] = fmaf(dA[11], h[11], dtx * RQF(rq, 23));  y3 = fmaf(h[11], RQF(rq, 39), y3);
            h[12] = fmaf(dA[12], h[12], dtx * RQF(rq, 24));  y0 = fmaf(h[12], RQF(rq, 40), y0);
            h[13] = fmaf(dA[13], h[13], dtx * RQF(rq, 25));  y1 = fmaf(h[13], RQF(rq, 41), y1);
            h[14] = fmaf(dA[14], h[14], dtx * RQF(rq, 26));  y2 = fmaf(h[14], RQF(rq, 42), y2);
            h[15] = fmaf(dA[15], h[15], dtx * RQF(rq, 27));  y3 = fmaf(h[15], RQF(rq, 43), y3);
            yk[(size_t)s * DM] = (y0 + y1) + (y2 + y3) + Dval * xv;
        }
    }

    if (PHASE == 1) {
#pragma unroll
        for (int n = 0; n < NS; ++n) {
            carry[cbase + n] = h[n];
            aprod[cbase + n] = exp2f(dtsum * Avl2[n]);   // prod of dA == exp(Av * sum dt)
        }
    }
}

// ---------------- phase 2: inter-chunk sequential fixup ----------------
__global__ __launch_bounds__(192) void fix_kernel(float* __restrict__ carry,
                                                  const float* __restrict__ aprod) {
    int idx = blockIdx.x * DM + threadIdx.x;     // 128*192 = 24576 = B*K*D*N
    int n = idx & (NS - 1);
    int dn = idx >> 4;
    int dd = dn % DM;
    int bkc = dn / DM;
    size_t base = ((size_t)bkc * NCH * DM + dd) * NS + n;
    const size_t stride = (size_t)DM * NS;
    float hp = 0.f;
#pragma unroll 4
    for (int c = 0; c < NCH; ++c) {
        size_t off = base + (size_t)c * stride;
        float P = aprod[off];
        float Cr = carry[off];
        carry[off] = hp;                 // state entering chunk c
        hp = fmaf(P, hp, Cr);
    }
}

// ---------------- projection: xdbl[bk][l][c] = sum_d xs[b,k,d,l] * W[k,c,d] ----------------
__global__ __launch_bounds__(256) void proj_kernel(const float* __restrict__ x,
                                                   const float* __restrict__ xpw,
                                                   float* __restrict__ xdbl) {
    int blk = blockIdx.x;                    // B*K*(L/TLP) = 512
    int ltile = blk % (LL / TLP);
    int bk = blk / (LL / TLP);
    int k = bk & 3;
    int b = bk >> 2;
    int l0 = ltile * TLP;

    __shared__ float xt[DM * (TLP + 1)];     // transposed tile, stride 65 -> conflict-free reads

    {
        int li = threadIdx.x >> 2;
        int d0 = (threadIdx.x & 3) * 48;
        int s = spatial_idx(k, l0 + li);
        const float4* xr = (const float4*)(x + ((size_t)b * LL + s) * DM + d0);
#pragma unroll
        for (int q = 0; q < 12; ++q) {
            float4 v = xr[q];
            int d = d0 + q * 4;
            xt[(d + 0) * (TLP + 1) + li] = v.x;
            xt[(d + 1) * (TLP + 1) + li] = v.y;
            xt[(d + 2) * (TLP + 1) + li] = v.z;
            xt[(d + 3) * (TLP + 1) + li] = v.w;
        }
    }
    __syncthreads();

    int lane = threadIdx.x & 63;
    int wv = threadIdx.x >> 6;               // 0..3
    int c0 = __builtin_amdgcn_readfirstlane(wv * 11);
    const float* wk = xpw + (size_t)k * CPROJ * DM;

    float acc[11];
#pragma unroll
    for (int ci = 0; ci < 11; ++ci) acc[ci] = 0.f;

    for (int d = 0; d < DM; ++d) {
        float xv = xt[d * (TLP + 1) + lane];
#pragma unroll
        for (int ci = 0; ci < 11; ++ci)
            acc[ci] = fmaf(xv, wk[(size_t)(c0 + ci) * DM + d], acc[ci]);
    }
    float* orow = xdbl + ((size_t)bk * LL + l0 + lane) * CPAD;
#pragma unroll
    for (int ci = 0; ci < 11; ++ci) orow[c0 + ci] = acc[ci];
}

// ---------------- LayerNorm over D=192 with 4-direction merge, wave per row ----------------
__global__ __launch_bounds__(256) void ln_kernel(const float* __restrict__ ybuf,
                                                 const float* __restrict__ lnw,
                                                 const float* __restrict__ lnb,
                                                 float* __restrict__ out) {
    const size_t SEG = (size_t)B_SZ * LL * DM;
    int row = blockIdx.x * 4 + (threadIdx.x >> 6);   // B*L rows
    int lane = threadIdx.x & 63;
    const float* yr = ybuf + (size_t)row * DM;
    float v0 = 0.f, v1 = 0.f, v2 = 0.f;
#pragma unroll
    for (int kq = 0; kq < KD; ++kq) {
        const float* p = yr + kq * SEG;
        v0 += p[lane];
        v1 += p[lane + 64];
        v2 += p[lane + 128];
    }
    float s = v0 + v1 + v2;
    float sq = v0 * v0 + v1 * v1 + v2 * v2;
#pragma unroll
    for (int off = 32; off >= 1; off >>= 1) {
        s += __shfl_xor(s, off, 64);
        sq += __shfl_xor(sq, off, 64);
    }
    float mu = s * (1.f / DM);
    float var = sq * (1.f / DM) - mu * mu;
    float inv = rsqrtf(var + 1e-5f);
    float* orow = out + (size_t)row * DM;
    orow[lane]       = (v0 - mu) * inv * lnw[lane]       + lnb[lane];
    orow[lane + 64]  = (v1 - mu) * inv * lnw[lane + 64]  + lnb[lane + 64];
    orow[lane + 128] = (v2 - mu) * inv * lnw[lane + 128] + lnb[lane + 128];
}

extern "C" void kernel_launch(void* const* d_in, const int* in_sizes, int n_in,
                              void* d_out, int out_size, void* d_ws, size_t ws_size,
                              hipStream_t stream) {
    const float* x    = (const float*)d_in[0];
    const float* xpw  = (const float*)d_in[1];
    const float* dtw  = (const float*)d_in[2];
    const float* dtb  = (const float*)d_in[3];
    const float* Alog = (const float*)d_in[4];
    const float* Ds   = (const float*)d_in[5];
    const float* lnw  = (const float*)d_in[6];
    const float* lnb  = (const float*)d_in[7];
    float* out = (float*)d_out;

    const size_t F_XD = (size_t)B_SZ * KD * LL * CPAD;       // 1,572,864 floats (6.3 MB)
    const size_t F_CR = (size_t)B_SZ * KD * NCH * DM * NS;   // 6,291,456 floats (25.2 MB)

    float* ws    = (float*)d_ws;
    float* xdbl  = ws;
    float* carry = xdbl + F_XD;
    float* aprod = carry + F_CR;
    float* ybuf4 = aprod + F_CR;                             // 4 segments, 25.2 MB

    proj_kernel<<<B_SZ * KD * (LL / TLP), 256, 0, stream>>>(x, xpw, xdbl);
    scan_kernel<1><<<NBLK, DM, 0, stream>>>(x, xdbl, dtw, dtb, Alog, Ds, carry, aprod, ybuf4);
    fix_kernel<<<128, DM, 0, stream>>>(carry, aprod);
    scan_kernel<3><<<NBLK, DM, 0, stream>>>(x, xdbl, dtw, dtb, Alog, Ds, carry, aprod, ybuf4);
    ln_kernel<<<(B_SZ * LL) / 4, 256, 0, stream>>>(ybuf4, lnw, lnb, out);
}

// Round 9
// 131.924 us; speedup vs baseline: 1.3387x; 1.3387x over previous
//
#include <hip/hip_runtime.h>
#include <math.h>

#define B_SZ 2
#define HH 64
#define WW 64
#define DM 192
#define NS 16
#define RR 12
#define KD 4
#define LL (HH * WW)           // 4096
#define CPROJ (RR + 2 * NS)    // 44
#define CPAD 48
#define NCH 256
#define CH (LL / NCH)          // 16 steps per chunk
#define NBLK (B_SZ * KD * NCH) // 2048 blocks
#define TLP 64                 // l-tile per proj block
#define LOG2E 1.44269504088896340736f
#define LN2F 0.69314718055994530942f

// spatial index (row-major h*W+w) that scan position t of direction k touches
__device__ __forceinline__ int spatial_idx(int k, int t) {
    if (k == 0) return t;
    if (k == 1) return ((t & 63) << 6) | (t >> 6);          // t = w*H + h -> l = h*W + w
    if (k == 2) return LL - 1 - t;
    int tp = LL - 1 - t;
    return ((tp & 63) << 6) | (tp >> 6);
}

__device__ __forceinline__ void compute_dA(float dt, const float* Avl2, bool pw, float* dA) {
    if (pw) {
        float e1 = exp2f(dt * Avl2[0]);
        dA[0] = e1;
        dA[1] = e1 * e1;
        dA[2] = dA[1] * e1;
        dA[3] = dA[1] * dA[1];
        dA[4] = dA[3] * e1;
        dA[5] = dA[3] * dA[1];
        dA[6] = dA[3] * dA[2];
        dA[7] = dA[3] * dA[3];
        dA[8] = dA[7] * e1;
        dA[9] = dA[7] * dA[1];
        dA[10] = dA[7] * dA[2];
        dA[11] = dA[7] * dA[3];
        dA[12] = dA[7] * dA[4];
        dA[13] = dA[7] * dA[5];
        dA[14] = dA[7] * dA[6];
        dA[15] = dA[7] * dA[7];
    } else {
#pragma unroll
        for (int n = 0; n < NS; ++n) dA[n] = exp2f(dt * Avl2[n]);
    }
}

__device__ __forceinline__ void load_params(int kd, const float* __restrict__ dtw,
                                            const float* __restrict__ dtb,
                                            const float* __restrict__ Alogs,
                                            float* Wdt, float& bias, float* Avl2, bool& pw) {
#pragma unroll
    for (int r = 0; r < RR; ++r) Wdt[r] = dtw[(size_t)kd * RR + r];
    bias = dtb[kd];
#pragma unroll
    for (int n = 0; n < NS; ++n) Avl2[n] = -__expf(Alogs[(size_t)kd * NS + n]) * LOG2E;
    bool pws = true;
#pragma unroll
    for (int n = 0; n < NS; ++n)
        pws = pws && (fabsf(Avl2[n] - (float)(n + 1) * Avl2[0]) <= 1e-5f * fabsf(Avl2[n]) + 1e-30f);
    pw = (__all(pws ? 1 : 0) != 0);
}

// ---------------- chunked selective scan, phases 1 (carries) and 3 (emit y) ----------------
// NCH=256 -> 2048 blocks -> 8 blocks/CU (24 waves/CU) for latency hiding.
// unroll 4 + on-demand LDS reads keep VGPR low (r8 lesson: full unroll -> 256 VGPR -> 8% occ).
template <int PHASE>
__global__ __launch_bounds__(192) void scan_kernel(
    const float* __restrict__ x, const float* __restrict__ xdbl,
    const float* __restrict__ dtw, const float* __restrict__ dtb,
    const float* __restrict__ Alogs, const float* __restrict__ Ds,
    float* __restrict__ carry, float* __restrict__ aprod, float* __restrict__ ybuf4) {
    const int chunk = blockIdx.x & (NCH - 1);
    const int bk = blockIdx.x >> 8;
    const int k = bk & 3, b = bk >> 2;
    const int d = threadIdx.x;                 // 0..191
    const int kd = k * DM + d;
    const int tbase = chunk * CH;

    __shared__ float xds[CH * CPAD];           // 3 KB: xdbl chunk (16 rows x 48)

    // stage xdbl chunk: 192 float4, exactly 1 per thread
    {
        float4* dst = (float4*)xds;
        const float4* src = (const float4*)(xdbl + ((size_t)bk * LL + tbase) * CPAD);
        dst[threadIdx.x] = src[threadIdx.x];
    }
    __syncthreads();

    float Wdt[RR], bias, Avl2[NS];
    bool pw;
    load_params(kd, dtw, dtb, Alogs, Wdt, bias, Avl2, pw);
    const float Dval = (PHASE == 3) ? Ds[kd] : 0.f;

    const size_t cbase = ((size_t)blockIdx.x * DM + d) * NS;
    float h[NS];
    if (PHASE == 1) {
#pragma unroll
        for (int n = 0; n < NS; ++n) h[n] = 0.f;
    } else {
#pragma unroll
        for (int n = 0; n < NS; ++n) h[n] = carry[cbase + n];   // h_in from fix_kernel
    }
    float dtsum = 0.f;
    const float* xb = x + (size_t)b * LL * DM + d;
    float* yk = ybuf4 + (size_t)k * ((size_t)B_SZ * LL * DM) + (size_t)b * LL * DM + d;

#pragma unroll 4
    for (int tt = 0; tt < CH; ++tt) {
        const float4* r4 = (const float4*)(xds + tt * CPAD);
        // dt projection from rows 0..11, two-way split FMA chains
        float4 q0 = r4[0], q1 = r4[1], q2 = r4[2];
        float z0 = fmaf(q0.x, Wdt[0], fmaf(q0.z, Wdt[2], fmaf(q1.x, Wdt[4],
                   fmaf(q1.z, Wdt[6], fmaf(q2.x, Wdt[8], q2.z * Wdt[10])))));
        float z1 = fmaf(q0.y, Wdt[1], fmaf(q0.w, Wdt[3], fmaf(q1.y, Wdt[5],
                   fmaf(q1.w, Wdt[7], fmaf(q2.y, Wdt[9], q2.w * Wdt[11])))));
        float z = bias + z0 + z1;
        float dt = (z > 15.f) ? z : __log2f(1.f + exp2f(z * LOG2E)) * LN2F;
        int s = spatial_idx(k, tbase + tt);
        float xv = xb[(size_t)s * DM];
        float dtx = dt * xv;
        float dA[NS];
        compute_dA(dt, Avl2, pw, dA);
        if (PHASE == 1) {
            dtsum += dt;
            float4 Bq;
            Bq = r4[3];
            h[0]  = fmaf(dA[0],  h[0],  dtx * Bq.x);
            h[1]  = fmaf(dA[1],  h[1],  dtx * Bq.y);
            h[2]  = fmaf(dA[2],  h[2],  dtx * Bq.z);
            h[3]  = fmaf(dA[3],  h[3],  dtx * Bq.w);
            Bq = r4[4];
            h[4]  = fmaf(dA[4],  h[4],  dtx * Bq.x);
            h[5]  = fmaf(dA[5],  h[5],  dtx * Bq.y);
            h[6]  = fmaf(dA[6],  h[6],  dtx * Bq.z);
            h[7]  = fmaf(dA[7],  h[7],  dtx * Bq.w);
            Bq = r4[5];
            h[8]  = fmaf(dA[8],  h[8],  dtx * Bq.x);
            h[9]  = fmaf(dA[9],  h[9],  dtx * Bq.y);
            h[10] = fmaf(dA[10], h[10], dtx * Bq.z);
            h[11] = fmaf(dA[11], h[11], dtx * Bq.w);
            Bq = r4[6];
            h[12] = fmaf(dA[12], h[12], dtx * Bq.x);
            h[13] = fmaf(dA[13], h[13], dtx * Bq.y);
            h[14] = fmaf(dA[14], h[14], dtx * Bq.z);
            h[15] = fmaf(dA[15], h[15], dtx * Bq.w);
        } else {
            float y0, y1, y2, y3;
            float4 Bq, Cq;
            Bq = r4[3]; Cq = r4[7];
            h[0]  = fmaf(dA[0],  h[0],  dtx * Bq.x);  y0 = h[0] * Cq.x;
            h[1]  = fmaf(dA[1],  h[1],  dtx * Bq.y);  y1 = h[1] * Cq.y;
            h[2]  = fmaf(dA[2],  h[2],  dtx * Bq.z);  y2 = h[2] * Cq.z;
            h[3]  = fmaf(dA[3],  h[3],  dtx * Bq.w);  y3 = h[3] * Cq.w;
            Bq = r4[4]; Cq = r4[8];
            h[4]  = fmaf(dA[4],  h[4],  dtx * Bq.x);  y0 = fmaf(h[4],  Cq.x, y0);
            h[5]  = fmaf(dA[5],  h[5],  dtx * Bq.y);  y1 = fmaf(h[5],  Cq.y, y1);
            h[6]  = fmaf(dA[6],  h[6],  dtx * Bq.z);  y2 = fmaf(h[6],  Cq.z, y2);
            h[7]  = fmaf(dA[7],  h[7],  dtx * Bq.w);  y3 = fmaf(h[7],  Cq.w, y3);
            Bq = r4[5]; Cq = r4[9];
            h[8]  = fmaf(dA[8],  h[8],  dtx * Bq.x);  y0 = fmaf(h[8],  Cq.x, y0);
            h[9]  = fmaf(dA[9],  h[9],  dtx * Bq.y);  y1 = fmaf(h[9],  Cq.y, y1);
            h[10] = fmaf(dA[10], h[10], dtx * Bq.z);  y2 = fmaf(h[10], Cq.z, y2);
            h[11] = fmaf(dA[11], h[11], dtx * Bq.w);  y3 = fmaf(h[11], Cq.w, y3);
            Bq = r4[6]; Cq = r4[10];
            h[12] = fmaf(dA[12], h[12], dtx * Bq.x);  y0 = fmaf(h[12], Cq.x, y0);
            h[13] = fmaf(dA[13], h[13], dtx * Bq.y);  y1 = fmaf(h[13], Cq.y, y1);
            h[14] = fmaf(dA[14], h[14], dtx * Bq.z);  y2 = fmaf(h[14], Cq.z, y2);
            h[15] = fmaf(dA[15], h[15], dtx * Bq.w);  y3 = fmaf(h[15], Cq.w, y3);
            yk[(size_t)s * DM] = (y0 + y1) + (y2 + y3) + Dval * xv;
        }
    }

    if (PHASE == 1) {
#pragma unroll
        for (int n = 0; n < NS; ++n) {
            carry[cbase + n] = h[n];
            aprod[cbase + n] = exp2f(dtsum * Avl2[n]);   // prod of dA == exp(Av * sum dt)
        }
    }
}

// ---------------- phase 2: inter-chunk sequential fixup ----------------
__global__ __launch_bounds__(192) void fix_kernel(float* __restrict__ carry,
                                                  const float* __restrict__ aprod) {
    int idx = blockIdx.x * DM + threadIdx.x;     // 128*192 = 24576 = B*K*D*N
    int n = idx & (NS - 1);
    int dn = idx >> 4;
    int dd = dn % DM;
    int bkc = dn / DM;
    size_t base = ((size_t)bkc * NCH * DM + dd) * NS + n;
    const size_t stride = (size_t)DM * NS;
    float hp = 0.f;
#pragma unroll 4
    for (int c = 0; c < NCH; ++c) {
        size_t off = base + (size_t)c * stride;
        float P = aprod[off];
        float Cr = carry[off];
        carry[off] = hp;                 // state entering chunk c
        hp = fmaf(P, hp, Cr);
    }
}

// ---------------- projection: xdbl[bk][l][c] = sum_d xs[b,k,d,l] * W[k,c,d] ----------------
__global__ __launch_bounds__(256) void proj_kernel(const float* __restrict__ x,
                                                   const float* __restrict__ xpw,
                                                   float* __restrict__ xdbl) {
    int blk = blockIdx.x;                    // B*K*(L/TLP) = 512
    int ltile = blk % (LL / TLP);
    int bk = blk / (LL / TLP);
    int k = bk & 3;
    int b = bk >> 2;
    int l0 = ltile * TLP;

    __shared__ float xt[DM * (TLP + 1)];     // transposed tile, stride 65 -> conflict-free reads

    {
        int li = threadIdx.x >> 2;
        int d0 = (threadIdx.x & 3) * 48;
        int s = spatial_idx(k, l0 + li);
        const float4* xr = (const float4*)(x + ((size_t)b * LL + s) * DM + d0);
#pragma unroll
        for (int q = 0; q < 12; ++q) {
            float4 v = xr[q];
            int d = d0 + q * 4;
            xt[(d + 0) * (TLP + 1) + li] = v.x;
            xt[(d + 1) * (TLP + 1) + li] = v.y;
            xt[(d + 2) * (TLP + 1) + li] = v.z;
            xt[(d + 3) * (TLP + 1) + li] = v.w;
        }
    }
    __syncthreads();

    int lane = threadIdx.x & 63;
    int wv = threadIdx.x >> 6;               // 0..3
    int c0 = __builtin_amdgcn_readfirstlane(wv * 11);
    const float* wk = xpw + (size_t)k * CPROJ * DM;

    float acc[11];
#pragma unroll
    for (int ci = 0; ci < 11; ++ci) acc[ci] = 0.f;

    for (int d = 0; d < DM; ++d) {
        float xv = xt[d * (TLP + 1) + lane];
#pragma unroll
        for (int ci = 0; ci < 11; ++ci)
            acc[ci] = fmaf(xv, wk[(size_t)(c0 + ci) * DM + d], acc[ci]);
    }
    float* orow = xdbl + ((size_t)bk * LL + l0 + lane) * CPAD;
#pragma unroll
    for (int ci = 0; ci < 11; ++ci) orow[c0 + ci] = acc[ci];
}

// ---------------- LayerNorm over D=192 with 4-direction merge, wave per row ----------------
__global__ __launch_bounds__(256) void ln_kernel(const float* __restrict__ ybuf,
                                                 const float* __restrict__ lnw,
                                                 const float* __restrict__ lnb,
                                                 float* __restrict__ out) {
    const size_t SEG = (size_t)B_SZ * LL * DM;
    int row = blockIdx.x * 4 + (threadIdx.x >> 6);   // B*L rows
    int lane = threadIdx.x & 63;
    const float* yr = ybuf + (size_t)row * DM;
    float v0 = 0.f, v1 = 0.f, v2 = 0.f;
#pragma unroll
    for (int kq = 0; kq < KD; ++kq) {
        const float* p = yr + kq * SEG;
        v0 += p[lane];
        v1 += p[lane + 64];
        v2 += p[lane + 128];
    }
    float s = v0 + v1 + v2;
    float sq = v0 * v0 + v1 * v1 + v2 * v2;
#pragma unroll
    for (int off = 32; off >= 1; off >>= 1) {
        s += __shfl_xor(s, off, 64);
        sq += __shfl_xor(sq, off, 64);
    }
    float mu = s * (1.f / DM);
    float var = sq * (1.f / DM) - mu * mu;
    float inv = rsqrtf(var + 1e-5f);
    float* orow = out + (size_t)row * DM;
    orow[lane]       = (v0 - mu) * inv * lnw[lane]       + lnb[lane];
    orow[lane + 64]  = (v1 - mu) * inv * lnw[lane + 64]  + lnb[lane + 64];
    orow[lane + 128] = (v2 - mu) * inv * lnw[lane + 128] + lnb[lane + 128];
}

extern "C" void kernel_launch(void* const* d_in, const int* in_sizes, int n_in,
                              void* d_out, int out_size, void* d_ws, size_t ws_size,
                              hipStream_t stream) {
    const float* x    = (const float*)d_in[0];
    const float* xpw  = (const float*)d_in[1];
    const float* dtw  = (const float*)d_in[2];
    const float* dtb  = (const float*)d_in[3];
    const float* Alog = (const float*)d_in[4];
    const float* Ds   = (const float*)d_in[5];
    const float* lnw  = (const float*)d_in[6];
    const float* lnb  = (const float*)d_in[7];
    float* out = (float*)d_out;

    const size_t F_XD = (size_t)B_SZ * KD * LL * CPAD;       // 1,572,864 floats (6.3 MB)
    const size_t F_CR = (size_t)B_SZ * KD * NCH * DM * NS;   // 6,291,456 floats (25.2 MB)

    float* ws    = (float*)d_ws;
    float* xdbl  = ws;
    float* carry = xdbl + F_XD;
    float* aprod = carry + F_CR;
    float* ybuf4 = aprod + F_CR;                             // 4 segments, 25.2 MB

    proj_kernel<<<B_SZ * KD * (LL / TLP), 256, 0, stream>>>(x, xpw, xdbl);
    scan_kernel<1><<<NBLK, DM, 0, stream>>>(x, xdbl, dtw, dtb, Alog, Ds, carry, aprod, ybuf4);
    fix_kernel<<<128, DM, 0, stream>>>(carry, aprod);
    scan_kernel<3><<<NBLK, DM, 0, stream>>>(x, xdbl, dtw, dtb, Alog, Ds, carry, aprod, ybuf4);
    ln_kernel<<<(B_SZ * LL) / 4, 256, 0, stream>>>(ybuf4, lnw, lnb, out);
}

// Round 10
// 107.175 us; speedup vs baseline: 1.6478x; 1.2309x over previous
//
#include <hip/hip_runtime.h>
#include <math.h>

#define B_SZ 2
#define HH 64
#define WW 64
#define DM 192
#define NS 16
#define RR 12
#define KD 4
#define LL (HH * WW)           // 4096
#define CPROJ (RR + 2 * NS)    // 44
#define CPAD 48
#define NCH 128
#define CH (LL / NCH)          // 32 steps per chunk
#define NBLK (B_SZ * KD * NCH) // 1024 blocks
#define KDTOT (KD * DM)        // 768
#define TLP 64                 // l-tile per proj block
#define LOG2E 1.44269504088896340736f
#define LN2F 0.69314718055994530942f

// spatial index (row-major h*W+w) that scan position t of direction k touches
__device__ __forceinline__ int spatial_idx(int k, int t) {
    if (k == 0) return t;
    if (k == 1) return ((t & 63) << 6) | (t >> 6);          // t = w*H + h -> l = h*W + w
    if (k == 2) return LL - 1 - t;
    int tp = LL - 1 - t;
    return ((tp & 63) << 6) | (tp >> 6);
}

__device__ __forceinline__ void compute_dA(float dt, const float* Avl2, bool pw, float* dA) {
    if (pw) {
        float e1 = exp2f(dt * Avl2[0]);
        dA[0] = e1;
        dA[1] = e1 * e1;
        dA[2] = dA[1] * e1;
        dA[3] = dA[1] * dA[1];
        dA[4] = dA[3] * e1;
        dA[5] = dA[3] * dA[1];
        dA[6] = dA[3] * dA[2];
        dA[7] = dA[3] * dA[3];
        dA[8] = dA[7] * e1;
        dA[9] = dA[7] * dA[1];
        dA[10] = dA[7] * dA[2];
        dA[11] = dA[7] * dA[3];
        dA[12] = dA[7] * dA[4];
        dA[13] = dA[7] * dA[5];
        dA[14] = dA[7] * dA[6];
        dA[15] = dA[7] * dA[7];
    } else {
#pragma unroll
        for (int n = 0; n < NS; ++n) dA[n] = exp2f(dt * Avl2[n]);
    }
}

// ---------------- prep: transpose per-(k,d) params into coalesced [param][kd] layout ----------
// pbuf layout (floats): Wt[12][768] | At[16][768] | bt[768] | flg[768]
__global__ __launch_bounds__(192) void prep_kernel(const float* __restrict__ dtw,
                                                   const float* __restrict__ dtb,
                                                   const float* __restrict__ Alogs,
                                                   float* __restrict__ pbuf) {
    int kd = blockIdx.x * DM + threadIdx.x;    // 4 blocks x 192 = 768
    float* Wt  = pbuf;
    float* At  = pbuf + RR * KDTOT;
    float* bt  = At + NS * KDTOT;
    float* flg = bt + KDTOT;
#pragma unroll
    for (int r = 0; r < RR; ++r) Wt[r * KDTOT + kd] = dtw[(size_t)kd * RR + r];
    float Av[NS];
#pragma unroll
    for (int n = 0; n < NS; ++n) {
        Av[n] = -__expf(Alogs[(size_t)kd * NS + n]) * LOG2E;
        At[n * KDTOT + kd] = Av[n];
    }
    bt[kd] = dtb[kd];
    bool pws = true;
#pragma unroll
    for (int n = 0; n < NS; ++n)
        pws = pws && (fabsf(Av[n] - (float)(n + 1) * Av[0]) <= 1e-5f * fabsf(Av[n]) + 1e-30f);
    flg[kd] = pws ? 1.f : 0.f;
}

// ---------------- chunked selective scan, phases 1 (carries) and 3 (emit y) ----------------
// carry/aprod layout: [(bk*NCH+chunk)*NS + n][d]  -> all stores/loads lane-coalesced.
template <int PHASE>
__global__ __launch_bounds__(192) void scan_kernel(
    const float* __restrict__ x, const float* __restrict__ xdbl,
    const float* __restrict__ pbuf, const float* __restrict__ Ds,
    float* __restrict__ carry, float* __restrict__ aprod, float* __restrict__ ybuf4) {
    const int chunk = blockIdx.x & (NCH - 1);
    const int bk = blockIdx.x >> 7;
    const int k = bk & 3, b = bk >> 2;
    const int d = threadIdx.x;                 // 0..191
    const int kd = k * DM + d;
    const int tbase = chunk * CH;

    __shared__ float xds[CH * CPAD];           // 6 KB: xdbl chunk (32 rows x 48)

    // stage xdbl chunk: 384 float4, 2 per thread (issued before param loads)
    {
        float4* dst = (float4*)xds;
        const float4* src = (const float4*)(xdbl + ((size_t)bk * LL + tbase) * CPAD);
        dst[threadIdx.x] = src[threadIdx.x];
        dst[threadIdx.x + DM] = src[threadIdx.x + DM];
    }

    // coalesced param loads from pbuf
    const float* Wt  = pbuf;
    const float* At  = pbuf + RR * KDTOT;
    const float* bt  = At + NS * KDTOT;
    const float* flg = bt + KDTOT;
    float Wdt[RR], Avl2[NS];
#pragma unroll
    for (int r = 0; r < RR; ++r) Wdt[r] = Wt[r * KDTOT + kd];
#pragma unroll
    for (int n = 0; n < NS; ++n) Avl2[n] = At[n * KDTOT + kd];
    const float bias = bt[kd];
    const bool pw = (__all(flg[kd] != 0.f ? 1 : 0) != 0);
    const float Dval = (PHASE == 3) ? Ds[kd] : 0.f;

    __syncthreads();

    const size_t cbase = ((size_t)blockIdx.x * NS) * DM + d;   // + n*DM
    float h[NS];
    if (PHASE == 1) {
#pragma unroll
        for (int n = 0; n < NS; ++n) h[n] = 0.f;
    } else {
#pragma unroll
        for (int n = 0; n < NS; ++n) h[n] = carry[cbase + (size_t)n * DM];
    }
    float dtsum = 0.f;
    const float* xb = x + (size_t)b * LL * DM + d;
    float* yk = ybuf4 + (size_t)k * ((size_t)B_SZ * LL * DM) + (size_t)b * LL * DM + d;

    // 1-deep software pipeline on the per-step x value
    float xv_cur = xb[(size_t)spatial_idx(k, tbase) * DM];

#pragma unroll 4
    for (int tt = 0; tt < CH; ++tt) {
        int snext = spatial_idx(k, tbase + ((tt < CH - 1) ? (tt + 1) : 0));
        float xv_next = xb[(size_t)snext * DM];

        const float4* r4 = (const float4*)(xds + tt * CPAD);
        // dt projection from cols 0..11, two-way split FMA chains
        float4 q0 = r4[0], q1 = r4[1], q2 = r4[2];
        float z0 = fmaf(q0.x, Wdt[0], fmaf(q0.z, Wdt[2], fmaf(q1.x, Wdt[4],
                   fmaf(q1.z, Wdt[6], fmaf(q2.x, Wdt[8], q2.z * Wdt[10])))));
        float z1 = fmaf(q0.y, Wdt[1], fmaf(q0.w, Wdt[3], fmaf(q1.y, Wdt[5],
                   fmaf(q1.w, Wdt[7], fmaf(q2.y, Wdt[9], q2.w * Wdt[11])))));
        float z = bias + z0 + z1;
        float dt = (z > 15.f) ? z : __log2f(1.f + exp2f(z * LOG2E)) * LN2F;
        float dtx = dt * xv_cur;
        float dA[NS];
        compute_dA(dt, Avl2, pw, dA);
        if (PHASE == 1) {
            dtsum += dt;
            float4 Bq;
            Bq = r4[3];
            h[0]  = fmaf(dA[0],  h[0],  dtx * Bq.x);
            h[1]  = fmaf(dA[1],  h[1],  dtx * Bq.y);
            h[2]  = fmaf(dA[2],  h[2],  dtx * Bq.z);
            h[3]  = fmaf(dA[3],  h[3],  dtx * Bq.w);
            Bq = r4[4];
            h[4]  = fmaf(dA[4],  h[4],  dtx * Bq.x);
            h[5]  = fmaf(dA[5],  h[5],  dtx * Bq.y);
            h[6]  = fmaf(dA[6],  h[6],  dtx * Bq.z);
            h[7]  = fmaf(dA[7],  h[7],  dtx * Bq.w);
            Bq = r4[5];
            h[8]  = fmaf(dA[8],  h[8],  dtx * Bq.x);
            h[9]  = fmaf(dA[9],  h[9],  dtx * Bq.y);
            h[10] = fmaf(dA[10], h[10], dtx * Bq.z);
            h[11] = fmaf(dA[11], h[11], dtx * Bq.w);
            Bq = r4[6];
            h[12] = fmaf(dA[12], h[12], dtx * Bq.x);
            h[13] = fmaf(dA[13], h[13], dtx * Bq.y);
            h[14] = fmaf(dA[14], h[14], dtx * Bq.z);
            h[15] = fmaf(dA[15], h[15], dtx * Bq.w);
        } else {
            float y0, y1, y2, y3;
            float4 Bq, Cq;
            Bq = r4[3]; Cq = r4[7];
            h[0]  = fmaf(dA[0],  h[0],  dtx * Bq.x);  y0 = h[0] * Cq.x;
            h[1]  = fmaf(dA[1],  h[1],  dtx * Bq.y);  y1 = h[1] * Cq.y;
            h[2]  = fmaf(dA[2],  h[2],  dtx * Bq.z);  y2 = h[2] * Cq.z;
            h[3]  = fmaf(dA[3],  h[3],  dtx * Bq.w);  y3 = h[3] * Cq.w;
            Bq = r4[4]; Cq = r4[8];
            h[4]  = fmaf(dA[4],  h[4],  dtx * Bq.x);  y0 = fmaf(h[4],  Cq.x, y0);
            h[5]  = fmaf(dA[5],  h[5],  dtx * Bq.y);  y1 = fmaf(h[5],  Cq.y, y1);
            h[6]  = fmaf(dA[6],  h[6],  dtx * Bq.z);  y2 = fmaf(h[6],  Cq.z, y2);
            h[7]  = fmaf(dA[7],  h[7],  dtx * Bq.w);  y3 = fmaf(h[7],  Cq.w, y3);
            Bq = r4[5]; Cq = r4[9];
            h[8]  = fmaf(dA[8],  h[8],  dtx * Bq.x);  y0 = fmaf(h[8],  Cq.x, y0);
            h[9]  = fmaf(dA[9],  h[9],  dtx * Bq.y);  y1 = fmaf(h[9],  Cq.y, y1);
            h[10] = fmaf(dA[10], h[10], dtx * Bq.z);  y2 = fmaf(h[10], Cq.z, y2);
            h[11] = fmaf(dA[11], h[11], dtx * Bq.w);  y3 = fmaf(h[11], Cq.w, y3);
            Bq = r4[6]; Cq = r4[10];
            h[12] = fmaf(dA[12], h[12], dtx * Bq.x);  y0 = fmaf(h[12], Cq.x, y0);
            h[13] = fmaf(dA[13], h[13], dtx * Bq.y);  y1 = fmaf(h[13], Cq.y, y1);
            h[14] = fmaf(dA[14], h[14], dtx * Bq.z);  y2 = fmaf(h[14], Cq.z, y2);
            h[15] = fmaf(dA[15], h[15], dtx * Bq.w);  y3 = fmaf(h[15], Cq.w, y3);
            int scur = spatial_idx(k, tbase + tt);
            yk[(size_t)scur * DM] = (y0 + y1) + (y2 + y3) + Dval * xv_cur;
        }
        xv_cur = xv_next;
    }

    if (PHASE == 1) {
#pragma unroll
        for (int n = 0; n < NS; ++n) {
            carry[cbase + (size_t)n * DM] = h[n];
            aprod[cbase + (size_t)n * DM] = exp2f(dtsum * Avl2[n]);  // prod dA == exp(Av*sum dt)
        }
    }
}

// ---------------- phase 2: inter-chunk sequential fixup (coalesced layout) ----------------
__global__ __launch_bounds__(192) void fix_kernel(float* __restrict__ carry,
                                                  const float* __restrict__ aprod) {
    int idx = blockIdx.x * DM + threadIdx.x;     // 128*192 = 24576 = B*K*N*D
    int d = idx % DM;
    int r = idx / DM;                            // r = bk*NS + n
    int n = r & (NS - 1);
    int bk = r >> 4;
    size_t base = (((size_t)bk * NCH) * NS + n) * DM + d;
    const size_t stride = (size_t)NS * DM;       // next chunk
    float hp = 0.f;
#pragma unroll 8
    for (int c = 0; c < NCH; ++c) {
        size_t off = base + (size_t)c * stride;
        float P = aprod[off];
        float Cr = carry[off];
        carry[off] = hp;                 // state entering chunk c
        hp = fmaf(P, hp, Cr);
    }
}

// ---------------- projection: xdbl[bk][l][c] = sum_d xs[b,k,d,l] * W[k,c,d] ----------------
__global__ __launch_bounds__(256) void proj_kernel(const float* __restrict__ x,
                                                   const float* __restrict__ xpw,
                                                   float* __restrict__ xdbl) {
    int blk = blockIdx.x;                    // B*K*(L/TLP) = 512
    int ltile = blk % (LL / TLP);
    int bk = blk / (LL / TLP);
    int k = bk & 3;
    int b = bk >> 2;
    int l0 = ltile * TLP;

    __shared__ float xt[DM * (TLP + 1)];     // transposed tile, stride 65 -> conflict-free reads

    {
        int li = threadIdx.x >> 2;
        int d0 = (threadIdx.x & 3) * 48;
        int s = spatial_idx(k, l0 + li);
        const float4* xr = (const float4*)(x + ((size_t)b * LL + s) * DM + d0);
#pragma unroll
        for (int q = 0; q < 12; ++q) {
            float4 v = xr[q];
            int d = d0 + q * 4;
            xt[(d + 0) * (TLP + 1) + li] = v.x;
            xt[(d + 1) * (TLP + 1) + li] = v.y;
            xt[(d + 2) * (TLP + 1) + li] = v.z;
            xt[(d + 3) * (TLP + 1) + li] = v.w;
        }
    }
    __syncthreads();

    int lane = threadIdx.x & 63;
    int wv = threadIdx.x >> 6;               // 0..3
    int c0 = __builtin_amdgcn_readfirstlane(wv * 11);
    const float* wk = xpw + (size_t)k * CPROJ * DM;

    float acc[11];
#pragma unroll
    for (int ci = 0; ci < 11; ++ci) acc[ci] = 0.f;

    for (int d = 0; d < DM; ++d) {
        float xv = xt[d * (TLP + 1) + lane];
#pragma unroll
        for (int ci = 0; ci < 11; ++ci)
            acc[ci] = fmaf(xv, wk[(size_t)(c0 + ci) * DM + d], acc[ci]);
    }
    float* orow = xdbl + ((size_t)bk * LL + l0 + lane) * CPAD;
#pragma unroll
    for (int ci = 0; ci < 11; ++ci) orow[c0 + ci] = acc[ci];
}

// ---------------- LayerNorm over D=192 with 4-direction merge, wave per row ----------------
__global__ __launch_bounds__(256) void ln_kernel(const float* __restrict__ ybuf,
                                                 const float* __restrict__ lnw,
                                                 const float* __restrict__ lnb,
                                                 float* __restrict__ out) {
    const size_t SEG = (size_t)B_SZ * LL * DM;
    int row = blockIdx.x * 4 + (threadIdx.x >> 6);   // B*L rows
    int lane = threadIdx.x & 63;
    const float* yr = ybuf + (size_t)row * DM;
    float v0 = 0.f, v1 = 0.f, v2 = 0.f;
#pragma unroll
    for (int kq = 0; kq < KD; ++kq) {
        const float* p = yr + kq * SEG;
        v0 += p[lane];
        v1 += p[lane + 64];
        v2 += p[lane + 128];
    }
    float s = v0 + v1 + v2;
    float sq = v0 * v0 + v1 * v1 + v2 * v2;
#pragma unroll
    for (int off = 32; off >= 1; off >>= 1) {
        s += __shfl_xor(s, off, 64);
        sq += __shfl_xor(sq, off, 64);
    }
    float mu = s * (1.f / DM);
    float var = sq * (1.f / DM) - mu * mu;
    float inv = rsqrtf(var + 1e-5f);
    float* orow = out + (size_t)row * DM;
    orow[lane]       = (v0 - mu) * inv * lnw[lane]       + lnb[lane];
    orow[lane + 64]  = (v1 - mu) * inv * lnw[lane + 64]  + lnb[lane + 64];
    orow[lane + 128] = (v2 - mu) * inv * lnw[lane + 128] + lnb[lane + 128];
}

extern "C" void kernel_launch(void* const* d_in, const int* in_sizes, int n_in,
                              void* d_out, int out_size, void* d_ws, size_t ws_size,
                              hipStream_t stream) {
    const float* x    = (const float*)d_in[0];
    const float* xpw  = (const float*)d_in[1];
    const float* dtw  = (const float*)d_in[2];
    const float* dtb  = (const float*)d_in[3];
    const float* Alog = (const float*)d_in[4];
    const float* Ds   = (const float*)d_in[5];
    const float* lnw  = (const float*)d_in[6];
    const float* lnb  = (const float*)d_in[7];
    float* out = (float*)d_out;

    const size_t F_XD = (size_t)B_SZ * KD * LL * CPAD;       // 1,572,864 floats (6.3 MB)
    const size_t F_CR = (size_t)B_SZ * KD * NCH * DM * NS;   // 3,145,728 floats (12.6 MB)
    const size_t F_YB = (size_t)B_SZ * LL * DM;              // 1,572,864 floats (6.3 MB)

    float* ws    = (float*)d_ws;
    float* xdbl  = ws;
    float* carry = xdbl + F_XD;
    float* aprod = carry + F_CR;
    float* ybuf4 = aprod + F_CR;                             // 4 segments, 25.2 MB
    float* pbuf  = ybuf4 + 4 * F_YB;                         // (12+16+1+1)*768 floats

    prep_kernel<<<KDTOT / DM, DM, 0, stream>>>(dtw, dtb, Alog, pbuf);
    proj_kernel<<<B_SZ * KD * (LL / TLP), 256, 0, stream>>>(x, xpw, xdbl);
    scan_kernel<1><<<NBLK, DM, 0, stream>>>(x, xdbl, pbuf, Ds, carry, aprod, ybuf4);
    fix_kernel<<<128, DM, 0, stream>>>(carry, aprod);
    scan_kernel<3><<<NBLK, DM, 0, stream>>>(x, xdbl, pbuf, Ds, carry, aprod, ybuf4);
    ln_kernel<<<(B_SZ * LL) / 4, 256, 0, stream>>>(ybuf4, lnw, lnb, out);
}